// Round 3
// baseline (206.623 us; speedup 1.0000x reference)
//
#include <hip/hip_runtime.h>

#define T_SEQ 2048
#define NH 4
#define DH 64
#define PW 36  // Pw row stride in shorts: 72B rows -> uniform bank spread for b64 ops

typedef __bf16 bf16x8 __attribute__((ext_vector_type(8)));
typedef float f32x4 __attribute__((ext_vector_type(4)));
typedef unsigned short u16x8 __attribute__((ext_vector_type(8)));

__device__ __forceinline__ unsigned short f2bf_rne(float x) {
  unsigned int u = __builtin_bit_cast(unsigned int, x);
  u += 0x7fffu + ((u >> 16) & 1u);
  return (unsigned short)(u >> 16);
}
__device__ __forceinline__ float bf2f(unsigned short s) {
  unsigned int u = ((unsigned int)s) << 16;
  return __builtin_bit_cast(float, u);
}

// ---------------------------------------------------------------------------
// prep_w: transpose + hi/lo split W (256x256 f32) -> WtHi/WtLo [n][k] bf16.
// ---------------------------------------------------------------------------
__global__ void prep_w(const float* __restrict__ W,
                       unsigned short* __restrict__ WtHi,
                       unsigned short* __restrict__ WtLo) {
  __shared__ float ls[32][65];
  const int tid = threadIdx.x;
  const int k0 = (blockIdx.x >> 2) * 32;
  const int n0 = (blockIdx.x & 3) * 64;
#pragma unroll
  for (int i = 0; i < 8; i++) {
    int e = i * 256 + tid;
    int r = e >> 6, c = e & 63;
    ls[r][c] = W[(k0 + r) * 256 + n0 + c];
  }
  __syncthreads();
  const int n = tid & 63;
  const int part = tid >> 6;
  u16x8 vh, vl;
#pragma unroll
  for (int j = 0; j < 8; j++) {
    float w = ls[part * 8 + j][n];
    unsigned short h16 = f2bf_rne(w);
    vh[j] = h16;
    vl[j] = f2bf_rne(w - bf2f(h16));
  }
  size_t dst = (size_t)(n0 + n) * 256 + k0 + part * 8;
  *(u16x8*)&WtHi[dst] = vh;
  *(u16x8*)&WtLo[dst] = vl;
}

// ---------------------------------------------------------------------------
// wh_gemm: Wh = h @ W via split-bf16 MFMA (3-term, ~fp32 accurate).
//   Kb[bh][t][d] = bf16(Wh * sqrt(log2e/8)),  Vt[bh][d][t] = bf16(Wh)
// ktile stride 272 (conflict-free writes); vtile writes packed uint2.
// ---------------------------------------------------------------------------
__global__ __launch_bounds__(256, 2) void wh_gemm(
    const float* __restrict__ h,
    const unsigned short* __restrict__ WtHi,
    const unsigned short* __restrict__ WtLo,
    unsigned short* __restrict__ Kb, unsigned short* __restrict__ Vt) {
  __shared__ __align__(16) unsigned short ktile[32][272];
  __shared__ __align__(16) unsigned short vtile[256][40];
  const int tid = threadIdx.x;
  const int wave = tid >> 6, lane = tid & 63, l15 = lane & 15, quad = lane >> 4;
  const int m0b = blockIdx.x * 32;
  const int m0 = m0b + (wave & 1) * 16;
  const int n0w = (wave >> 1) * 128;
  f32x4 acc[8];
#pragma unroll
  for (int nt = 0; nt < 8; nt++) acc[nt] = (f32x4){0.f, 0.f, 0.f, 0.f};

  for (int kc = 0; kc < 8; kc++) {
    const float4* hp = (const float4*)&h[(size_t)(m0 + l15) * 256 + kc * 32 + quad * 8];
    float4 a0 = hp[0], a1 = hp[1];
    float xs[8] = {a0.x, a0.y, a0.z, a0.w, a1.x, a1.y, a1.z, a1.w};
    u16x8 ah, al;
#pragma unroll
    for (int j = 0; j < 8; j++) {
      unsigned short h16 = f2bf_rne(xs[j]);
      ah[j] = h16;
      al[j] = f2bf_rne(xs[j] - bf2f(h16));
    }
    bf16x8 ahi = __builtin_bit_cast(bf16x8, ah);
    bf16x8 alo = __builtin_bit_cast(bf16x8, al);
#pragma unroll
    for (int nt = 0; nt < 8; nt++) {
      size_t wb = (size_t)(n0w + nt * 16 + l15) * 256 + kc * 32 + quad * 8;
      bf16x8 bhi = *(const bf16x8*)&WtHi[wb];
      bf16x8 blo = *(const bf16x8*)&WtLo[wb];
      acc[nt] = __builtin_amdgcn_mfma_f32_16x16x32_bf16(ahi, bhi, acc[nt], 0, 0, 0);
      acc[nt] = __builtin_amdgcn_mfma_f32_16x16x32_bf16(alo, bhi, acc[nt], 0, 0, 0);
      acc[nt] = __builtin_amdgcn_mfma_f32_16x16x32_bf16(ahi, blo, acc[nt], 0, 0, 0);
    }
  }
  const float s1 = 0.424664717f;  // sqrt(log2(e)/8)
  const int tl = (wave & 1) * 16 + quad * 4;
#pragma unroll
  for (int nt = 0; nt < 8; nt++) {
    int n = n0w + nt * 16 + l15;
    ushort4 vp;
#pragma unroll
    for (int r = 0; r < 4; r++) {
      float v = acc[nt][r];
      ktile[tl + r][n] = f2bf_rne(v * s1);
      ((unsigned short*)&vp)[r] = f2bf_rne(v);
    }
    *(uint2*)&vtile[n][tl] = __builtin_bit_cast(uint2, vp);  // 4 t's packed
  }
  __syncthreads();
  {  // Kb out: 4 x b128 stores
    int t = tid >> 3, seg = tid & 7;
    int m = m0b + t, b = m >> 11, tt = m & 2047;
    int head = seg >> 1, d0 = (seg & 1) * 32;
    unsigned short* dst = &Kb[((size_t)(b * NH + head) * T_SEQ + tt) * DH + d0];
#pragma unroll
    for (int q = 0; q < 4; q++)
      *(u16x8*)&dst[q * 8] = *(const u16x8*)&ktile[t][seg * 32 + q * 8];
  }
  {  // Vt out: 4 x b128 stores
    int n = tid, head = n >> 6, d = n & 63;
    int b = m0b >> 11, t0 = m0b & 2047;
    unsigned short* dst = &Vt[((size_t)(b * NH + head) * DH + d) * T_SEQ + t0];
#pragma unroll
    for (int q = 0; q < 4; q++)
      *(u16x8*)&dst[q * 8] = *(const u16x8*)&vtile[n][q * 8];
  }
}

// ---------------------------------------------------------------------------
// attn v3: S^T formulation; block = (bh, 64-q tile) x 4 waves; each wave
// sweeps a disjoint 512-key range (4-way split-K) -> 4096 waves (~3-4/SIMD).
// K/V/Q frags straight from global (L2-resident per XCD); P round-trip via
// per-wave LDS (stride-36 rows, b64 ops, uniform banks). Partial (o, lsum)
// combined through LDS tree reusing the dead Pw region.
// ---------------------------------------------------------------------------
__global__ __launch_bounds__(256, 3) void attn(
    const unsigned short* __restrict__ Kb, const unsigned short* __restrict__ Vt,
    float* __restrict__ out) {
  __shared__ __align__(16) char smem[2 * 64 * 68 * 4];  // cbuf x2; Pw (18.4KB) aliases
  __shared__ float lbuf[4][64];
  __shared__ float inv_s[64];
  const int tid = threadIdx.x, wave = tid >> 6, lane = tid & 63;
  const int l15 = lane & 15, quad = lane >> 4;
  const int bh = blockIdx.x & 31;  // all 32 q-tiles of a bh land on XCD bh%8
  const int qt = blockIdx.x >> 5;
  const int q0 = qt * 64;
  const unsigned short* Kbh = Kb + (size_t)bh * T_SEQ * DH;
  const unsigned short* Vbh = Vt + (size_t)bh * DH * T_SEQ;
  unsigned short* Pw = (unsigned short*)smem + wave * 64 * PW;

  // Q B-frags for 64 q-rows (shared q-tile across waves)
  bf16x8 bq[4][2];
#pragma unroll
  for (int nt = 0; nt < 4; nt++)
#pragma unroll
    for (int kc = 0; kc < 2; kc++)
      bq[nt][kc] = *(const bf16x8*)&Kbh[(size_t)(q0 + nt * 16 + l15) * DH + kc * 32 + quad * 8];

  f32x4 o[4][4];
  float lsum[4] = {0.f, 0.f, 0.f, 0.f};
#pragma unroll
  for (int mt = 0; mt < 4; mt++)
#pragma unroll
    for (int dt = 0; dt < 4; dt++) o[mt][dt] = (f32x4){0.f, 0.f, 0.f, 0.f};

  int s0 = wave * 512;
  for (int it = 0; it < 16; it++, s0 += 32) {
    bf16x8 ka[2][2], va[4];
#pragma unroll
    for (int mt = 0; mt < 2; mt++)
#pragma unroll
      for (int kc = 0; kc < 2; kc++)
        ka[mt][kc] = *(const bf16x8*)&Kbh[(size_t)(s0 + mt * 16 + l15) * DH + kc * 32 + quad * 8];
#pragma unroll
    for (int dt = 0; dt < 4; dt++)
      va[dt] = *(const bf16x8*)&Vbh[(size_t)(dt * 16 + l15) * T_SEQ + s0 + quad * 8];

    // S^T tile (32 keys x 64 q): C-layout rows = keys -> b64 P writes
#pragma unroll
    for (int mt = 0; mt < 2; mt++) {
#pragma unroll
      for (int nt = 0; nt < 4; nt++) {
        f32x4 s = {0.f, 0.f, 0.f, 0.f};
        s = __builtin_amdgcn_mfma_f32_16x16x32_bf16(ka[mt][0], bq[nt][0], s, 0, 0, 0);
        s = __builtin_amdgcn_mfma_f32_16x16x32_bf16(ka[mt][1], bq[nt][1], s, 0, 0, 0);
        float v0 = s[0], v1 = s[1], v2 = s[2], v3 = s[3];
        float e0 = __builtin_amdgcn_exp2f(fmaxf(v0, 0.2f * v0));
        float e1 = __builtin_amdgcn_exp2f(fmaxf(v1, 0.2f * v1));
        float e2 = __builtin_amdgcn_exp2f(fmaxf(v2, 0.2f * v2));
        float e3 = __builtin_amdgcn_exp2f(fmaxf(v3, 0.2f * v3));
        lsum[nt] += (e0 + e1) + (e2 + e3);
        uint2 pk;
        pk.x = (__builtin_bit_cast(unsigned int, e1) & 0xffff0000u) |
               (__builtin_bit_cast(unsigned int, e0) >> 16);
        pk.y = (__builtin_bit_cast(unsigned int, e3) & 0xffff0000u) |
               (__builtin_bit_cast(unsigned int, e2) >> 16);
        *(uint2*)&Pw[(nt * 16 + l15) * PW + mt * 16 + quad * 4] = pk;
      }
    }
    __builtin_amdgcn_s_waitcnt(0xC07F);  // lgkmcnt(0): wave-local P round-trip

    // O += P V  (A-frag from Pw rows; two b64 reads, 72B rows are 8B-aligned)
#pragma unroll
    for (int mt = 0; mt < 4; mt++) {
      const unsigned short* pr = &Pw[(mt * 16 + l15) * PW + quad * 8];
      uint2 plo = *(const uint2*)pr;
      uint2 phi = *(const uint2*)(pr + 4);
      uint4 pu = {plo.x, plo.y, phi.x, phi.y};
      bf16x8 pa = __builtin_bit_cast(bf16x8, pu);
#pragma unroll
      for (int dt = 0; dt < 4; dt++)
        o[mt][dt] = __builtin_amdgcn_mfma_f32_16x16x32_bf16(pa, va[dt], o[mt][dt], 0, 0, 0);
    }
  }

  // ---- combine 4 wave-partials ----
#pragma unroll
  for (int nt = 0; nt < 4; nt++) {
    float l = lsum[nt];
    l += __shfl_xor(l, 16, 64);
    l += __shfl_xor(l, 32, 64);
    if (quad == 0) lbuf[wave][nt * 16 + l15] = l;
  }
  __syncthreads();  // B1: lbuf done, Pw dead
  float* cbuf0 = (float*)smem;
  float* cbuf1 = cbuf0 + 64 * 68;
  if (wave >= 2) {
    float* cb = (wave == 2) ? cbuf0 : cbuf1;
#pragma unroll
    for (int mt = 0; mt < 4; mt++)
#pragma unroll
      for (int dt = 0; dt < 4; dt++)
        *(f32x4*)&cb[(dt * 16 + l15) * 68 + mt * 16 + quad * 4] = o[mt][dt];
  }
  if (wave == 0) {
    float s = lbuf[0][lane] + lbuf[1][lane] + lbuf[2][lane] + lbuf[3][lane];
    inv_s[lane] = 1.0f / s;
  }
  __syncthreads();  // B2
  if (wave < 2) {
    float* cb = (wave == 0) ? cbuf0 : cbuf1;
#pragma unroll
    for (int mt = 0; mt < 4; mt++)
#pragma unroll
      for (int dt = 0; dt < 4; dt++)
        o[mt][dt] += *(const f32x4*)&cb[(dt * 16 + l15) * 68 + mt * 16 + quad * 4];
  }
  __syncthreads();  // B3
  if (wave == 1) {
#pragma unroll
    for (int mt = 0; mt < 4; mt++)
#pragma unroll
      for (int dt = 0; dt < 4; dt++)
        *(f32x4*)&cbuf0[(dt * 16 + l15) * 68 + mt * 16 + quad * 4] = o[mt][dt];
  }
  __syncthreads();  // B4
  if (wave == 0) {
#pragma unroll
    for (int mt = 0; mt < 4; mt++)
#pragma unroll
      for (int dt = 0; dt < 4; dt++)
        o[mt][dt] += *(const f32x4*)&cbuf0[(dt * 16 + l15) * 68 + mt * 16 + quad * 4];
    const int b = bh >> 2, head = bh & 3;
#pragma unroll
    for (int mt = 0; mt < 4; mt++) {
#pragma unroll
      for (int r = 0; r < 4; r++) {
        int q = mt * 16 + quad * 4 + r;
        float iv = inv_s[q];
        float* dst = &out[((size_t)b * T_SEQ + q0 + q) * 256 + head * 64];
#pragma unroll
        for (int dt = 0; dt < 4; dt++) dst[dt * 16 + l15] = o[mt][dt][r] * iv;
      }
    }
  }
}

extern "C" void kernel_launch(void* const* d_in, const int* in_sizes, int n_in,
                              void* d_out, int out_size, void* d_ws, size_t ws_size,
                              hipStream_t stream) {
  const float* h = (const float*)d_in[0];
  const float* W = (const float*)d_in[1];
  float* out = (float*)d_out;
  unsigned short* Kb = (unsigned short*)d_ws;            // 8 MB
  unsigned short* Vt = Kb + (size_t)32 * T_SEQ * DH;     // 8 MB
  unsigned short* WtHi = (unsigned short*)out;           // head of d_out; attn overwrites later
  unsigned short* WtLo = WtHi + 65536;
  prep_w<<<32, 256, 0, stream>>>(W, WtHi, WtLo);
  wh_gemm<<<512, 256, 0, stream>>>(h, WtHi, WtLo, Kb, Vt);
  attn<<<1024, 256, 0, stream>>>(Kb, Vt, out);
}

// Round 4
// 182.035 us; speedup vs baseline: 1.1351x; 1.1351x over previous
//
#include <hip/hip_runtime.h>

#define T_SEQ 2048
#define NH 4
#define DH 64

typedef __bf16 bf16x8 __attribute__((ext_vector_type(8)));
typedef float f32x4 __attribute__((ext_vector_type(4)));
typedef unsigned short u16x8 __attribute__((ext_vector_type(8)));

__device__ __forceinline__ unsigned short f2bf_rne(float x) {
  unsigned int u = __builtin_bit_cast(unsigned int, x);
  u += 0x7fffu + ((u >> 16) & 1u);
  return (unsigned short)(u >> 16);
}
__device__ __forceinline__ float bf2f(unsigned short s) {
  unsigned int u = ((unsigned int)s) << 16;
  return __builtin_bit_cast(float, u);
}

// ---------------------------------------------------------------------------
// prep_w: transpose + hi/lo split W (256x256 f32) -> WtHi/WtLo [n][k] bf16.
// ---------------------------------------------------------------------------
__global__ void prep_w(const float* __restrict__ W,
                       unsigned short* __restrict__ WtHi,
                       unsigned short* __restrict__ WtLo) {
  __shared__ float ls[32][65];
  const int tid = threadIdx.x;
  const int k0 = (blockIdx.x >> 2) * 32;
  const int n0 = (blockIdx.x & 3) * 64;
#pragma unroll
  for (int i = 0; i < 8; i++) {
    int e = i * 256 + tid;
    int r = e >> 6, c = e & 63;
    ls[r][c] = W[(k0 + r) * 256 + n0 + c];
  }
  __syncthreads();
  const int n = tid & 63;
  const int part = tid >> 6;
  u16x8 vh, vl;
#pragma unroll
  for (int j = 0; j < 8; j++) {
    float w = ls[part * 8 + j][n];
    unsigned short h16 = f2bf_rne(w);
    vh[j] = h16;
    vl[j] = f2bf_rne(w - bf2f(h16));
  }
  size_t dst = (size_t)(n0 + n) * 256 + k0 + part * 8;
  *(u16x8*)&WtHi[dst] = vh;
  *(u16x8*)&WtLo[dst] = vl;
}

// ---------------------------------------------------------------------------
// wh_gemm: Wh = h @ W via split-bf16 MFMA (3-term, ~fp32 accurate).
//   Kb[bh][t][d] = bf16(Wh * sqrt(log2e/8))            (Q and K, natural t)
//   Vs[bh][d][sigma(t)] = bf16(Wh)                     (PV B-operand, key-
//     permuted: pos g*32+quad*8+half*4+j <-> t g*32+half*16+quad*4+j, so the
//     attn PV B-frag is one b128 and the A-frag is in-lane)
// ---------------------------------------------------------------------------
__global__ __launch_bounds__(256, 2) void wh_gemm(
    const float* __restrict__ h,
    const unsigned short* __restrict__ WtHi,
    const unsigned short* __restrict__ WtLo,
    unsigned short* __restrict__ Kb, unsigned short* __restrict__ Vs) {
  __shared__ __align__(16) unsigned short ktile[32][272];
  __shared__ __align__(16) unsigned short vtile[256][40];
  const int tid = threadIdx.x;
  const int wave = tid >> 6, lane = tid & 63, l15 = lane & 15, quad = lane >> 4;
  const int m0b = blockIdx.x * 32;
  const int m0 = m0b + (wave & 1) * 16;
  const int n0w = (wave >> 1) * 128;
  f32x4 acc[8];
#pragma unroll
  for (int nt = 0; nt < 8; nt++) acc[nt] = (f32x4){0.f, 0.f, 0.f, 0.f};

  for (int kc = 0; kc < 8; kc++) {
    const float4* hp = (const float4*)&h[(size_t)(m0 + l15) * 256 + kc * 32 + quad * 8];
    float4 a0 = hp[0], a1 = hp[1];
    float xs[8] = {a0.x, a0.y, a0.z, a0.w, a1.x, a1.y, a1.z, a1.w};
    u16x8 ah, al;
#pragma unroll
    for (int j = 0; j < 8; j++) {
      unsigned short h16 = f2bf_rne(xs[j]);
      ah[j] = h16;
      al[j] = f2bf_rne(xs[j] - bf2f(h16));
    }
    bf16x8 ahi = __builtin_bit_cast(bf16x8, ah);
    bf16x8 alo = __builtin_bit_cast(bf16x8, al);
#pragma unroll
    for (int nt = 0; nt < 8; nt++) {
      size_t wb = (size_t)(n0w + nt * 16 + l15) * 256 + kc * 32 + quad * 8;
      bf16x8 bhi = *(const bf16x8*)&WtHi[wb];
      bf16x8 blo = *(const bf16x8*)&WtLo[wb];
      acc[nt] = __builtin_amdgcn_mfma_f32_16x16x32_bf16(ahi, bhi, acc[nt], 0, 0, 0);
      acc[nt] = __builtin_amdgcn_mfma_f32_16x16x32_bf16(alo, bhi, acc[nt], 0, 0, 0);
      acc[nt] = __builtin_amdgcn_mfma_f32_16x16x32_bf16(ahi, blo, acc[nt], 0, 0, 0);
    }
  }
  const float s1 = 0.424664717f;  // sqrt(log2(e)/8)
  const int tl = (wave & 1) * 16 + quad * 4;
#pragma unroll
  for (int nt = 0; nt < 8; nt++) {
    int n = n0w + nt * 16 + l15;
    ushort4 vp;
#pragma unroll
    for (int r = 0; r < 4; r++) {
      float v = acc[nt][r];
      ktile[tl + r][n] = f2bf_rne(v * s1);
      ((unsigned short*)&vp)[r] = f2bf_rne(v);
    }
    *(uint2*)&vtile[n][tl] = __builtin_bit_cast(uint2, vp);  // 4 t's packed
  }
  __syncthreads();
  {  // Kb out: 4 x b128 stores (natural t order)
    int t = tid >> 3, seg = tid & 7;
    int m = m0b + t, b = m >> 11, tt = m & 2047;
    int head = seg >> 1, d0 = (seg & 1) * 32;
    unsigned short* dst = &Kb[((size_t)(b * NH + head) * T_SEQ + tt) * DH + d0];
#pragma unroll
    for (int q = 0; q < 4; q++)
      *(u16x8*)&dst[q * 8] = *(const u16x8*)&ktile[t][seg * 32 + q * 8];
  }
  {  // Vs out: 4 x b128 stores in sigma order (block's 32 t's = one group)
    int n = tid, head = n >> 6, d = n & 63;
    int b = m0b >> 11, t0 = m0b & 2047;
    unsigned short* dst = &Vs[((size_t)(b * NH + head) * DH + d) * T_SEQ + t0];
#pragma unroll
    for (int q = 0; q < 4; q++) {
      uint2 lo = *(const uint2*)&vtile[n][q * 4];        // t-local q*4..+3
      uint2 hi = *(const uint2*)&vtile[n][16 + q * 4];   // t-local 16+q*4..+3
      uint4 pk = {lo.x, lo.y, hi.x, hi.y};
      *(uint4*)&dst[q * 8] = pk;
    }
  }
}

// ---------------------------------------------------------------------------
// attn v4: S^T + in-lane P. Block = (bh, 64-q tile), 4 waves each sweeping a
// disjoint 512-key range. Hot loop touches NO LDS: K/V frags stream from
// global (L2-resident), P goes C-layout -> packed regs -> PV A-frag in-lane
// (V is sigma-permuted to make the interleave contiguous). Same-register
// prefetch gives ~1 iter of latency cover. Combine tree once at the end.
// ---------------------------------------------------------------------------
__global__ __launch_bounds__(256, 3) void attn(
    const unsigned short* __restrict__ Kb, const unsigned short* __restrict__ Vs,
    float* __restrict__ out) {
  __shared__ __align__(16) float cbuf[2][64 * 68];
  __shared__ float lbuf[4][64];
  __shared__ float inv_s[64];
  const int tid = threadIdx.x, wave = tid >> 6, lane = tid & 63;
  const int l15 = lane & 15, quad = lane >> 4;
  const int bh = blockIdx.x & 31;  // all 32 q-tiles of a bh land on XCD bh%8
  const int qt = blockIdx.x >> 5;
  const int q0 = qt * 64;
  const unsigned short* Kbh = Kb + (size_t)bh * T_SEQ * DH;
  const unsigned short* Vbh = Vs + (size_t)bh * DH * T_SEQ;

  // Q B-frags for the 64 shared q-rows
  bf16x8 bq[4][2];
#pragma unroll
  for (int nt = 0; nt < 4; nt++)
#pragma unroll
    for (int kc = 0; kc < 2; kc++)
      bq[nt][kc] = *(const bf16x8*)&Kbh[(size_t)(q0 + nt * 16 + l15) * DH + kc * 32 + quad * 8];

  f32x4 o[4][4];
  float lsum[4] = {0.f, 0.f, 0.f, 0.f};
#pragma unroll
  for (int mt = 0; mt < 4; mt++)
#pragma unroll
    for (int dt = 0; dt < 4; dt++) o[mt][dt] = (f32x4){0.f, 0.f, 0.f, 0.f};

  const int sbase = wave * 512;
  bf16x8 ka[2][2], vb[4];
#pragma unroll
  for (int mt = 0; mt < 2; mt++)
#pragma unroll
    for (int kc = 0; kc < 2; kc++)
      ka[mt][kc] = *(const bf16x8*)&Kbh[(size_t)(sbase + mt * 16 + l15) * DH + kc * 32 + quad * 8];
#pragma unroll
  for (int dt = 0; dt < 4; dt++)
    vb[dt] = *(const bf16x8*)&Vbh[(size_t)(dt * 16 + l15) * T_SEQ + sbase + quad * 8];

  for (int it = 0; it < 16; it++) {
    const int nxt = sbase + ((it == 15) ? it : it + 1) * 32;
    // S^T = K.Q^T : 32 keys x 64 q
    f32x4 s[2][4];
#pragma unroll
    for (int mt = 0; mt < 2; mt++)
#pragma unroll
      for (int nt = 0; nt < 4; nt++) {
        f32x4 c = {0.f, 0.f, 0.f, 0.f};
        c = __builtin_amdgcn_mfma_f32_16x16x32_bf16(ka[mt][0], bq[nt][0], c, 0, 0, 0);
        c = __builtin_amdgcn_mfma_f32_16x16x32_bf16(ka[mt][1], bq[nt][1], c, 0, 0, 0);
        s[mt][nt] = c;
      }
    // prefetch next K frags (ka dead after S phase)
#pragma unroll
    for (int mt = 0; mt < 2; mt++)
#pragma unroll
      for (int kc = 0; kc < 2; kc++)
        ka[mt][kc] = *(const bf16x8*)&Kbh[(size_t)(nxt + mt * 16 + l15) * DH + kc * 32 + quad * 8];

    // exp2(leaky) + pack: lane holds q=nt*16+l15, keys mt*16+quad*4+r
    uint2 pk[2][4];
#pragma unroll
    for (int mt = 0; mt < 2; mt++)
#pragma unroll
      for (int nt = 0; nt < 4; nt++) {
        float v0 = s[mt][nt][0], v1 = s[mt][nt][1];
        float v2 = s[mt][nt][2], v3 = s[mt][nt][3];
        float e0 = __builtin_amdgcn_exp2f(fmaxf(v0, 0.2f * v0));
        float e1 = __builtin_amdgcn_exp2f(fmaxf(v1, 0.2f * v1));
        float e2 = __builtin_amdgcn_exp2f(fmaxf(v2, 0.2f * v2));
        float e3 = __builtin_amdgcn_exp2f(fmaxf(v3, 0.2f * v3));
        lsum[nt] += (e0 + e1) + (e2 + e3);
        pk[mt][nt].x = (__builtin_bit_cast(unsigned int, e1) & 0xffff0000u) |
                       (__builtin_bit_cast(unsigned int, e0) >> 16);
        pk[mt][nt].y = (__builtin_bit_cast(unsigned int, e3) & 0xffff0000u) |
                       (__builtin_bit_cast(unsigned int, e2) >> 16);
      }

    // O += P V : A-frag built in-lane (sigma-matched), B-frag = vb
#pragma unroll
    for (int mq = 0; mq < 4; mq++) {
      uint4 pu = {pk[0][mq].x, pk[0][mq].y, pk[1][mq].x, pk[1][mq].y};
      bf16x8 pa = __builtin_bit_cast(bf16x8, pu);
#pragma unroll
      for (int dt = 0; dt < 4; dt++)
        o[mq][dt] = __builtin_amdgcn_mfma_f32_16x16x32_bf16(pa, vb[dt], o[mq][dt], 0, 0, 0);
    }
    // prefetch next V frags (vb dead after PV phase)
#pragma unroll
    for (int dt = 0; dt < 4; dt++)
      vb[dt] = *(const bf16x8*)&Vbh[(size_t)(dt * 16 + l15) * T_SEQ + nxt + quad * 8];
  }

  // ---- combine 4 wave-partials (verified R3 tree) ----
#pragma unroll
  for (int nt = 0; nt < 4; nt++) {
    float l = lsum[nt];
    l += __shfl_xor(l, 16, 64);
    l += __shfl_xor(l, 32, 64);
    if (quad == 0) lbuf[wave][nt * 16 + l15] = l;
  }
  __syncthreads();  // B1
  if (wave >= 2) {
    float* cb = cbuf[wave - 2];
#pragma unroll
    for (int mt = 0; mt < 4; mt++)
#pragma unroll
      for (int dt = 0; dt < 4; dt++)
        *(f32x4*)&cb[(dt * 16 + l15) * 68 + mt * 16 + quad * 4] = o[mt][dt];
  }
  if (wave == 0) {
    float s = lbuf[0][lane] + lbuf[1][lane] + lbuf[2][lane] + lbuf[3][lane];
    inv_s[lane] = 1.0f / s;
  }
  __syncthreads();  // B2
  if (wave < 2) {
    float* cb = cbuf[wave];
#pragma unroll
    for (int mt = 0; mt < 4; mt++)
#pragma unroll
      for (int dt = 0; dt < 4; dt++)
        o[mt][dt] += *(const f32x4*)&cb[(dt * 16 + l15) * 68 + mt * 16 + quad * 4];
  }
  __syncthreads();  // B3
  if (wave == 1) {
#pragma unroll
    for (int mt = 0; mt < 4; mt++)
#pragma unroll
      for (int dt = 0; dt < 4; dt++)
        *(f32x4*)&cbuf[0][(dt * 16 + l15) * 68 + mt * 16 + quad * 4] = o[mt][dt];
  }
  __syncthreads();  // B4
  if (wave == 0) {
#pragma unroll
    for (int mt = 0; mt < 4; mt++)
#pragma unroll
      for (int dt = 0; dt < 4; dt++)
        o[mt][dt] += *(const f32x4*)&cbuf[0][(dt * 16 + l15) * 68 + mt * 16 + quad * 4];
    const int b = bh >> 2, head = bh & 3;
#pragma unroll
    for (int mt = 0; mt < 4; mt++) {
#pragma unroll
      for (int r = 0; r < 4; r++) {
        int q = mt * 16 + quad * 4 + r;
        float iv = inv_s[q];
        float* dst = &out[((size_t)b * T_SEQ + q0 + q) * 256 + head * 64];
#pragma unroll
        for (int dt = 0; dt < 4; dt++) dst[dt * 16 + l15] = o[mt][dt][r] * iv;
      }
    }
  }
}

extern "C" void kernel_launch(void* const* d_in, const int* in_sizes, int n_in,
                              void* d_out, int out_size, void* d_ws, size_t ws_size,
                              hipStream_t stream) {
  const float* h = (const float*)d_in[0];
  const float* W = (const float*)d_in[1];
  float* out = (float*)d_out;
  unsigned short* Kb = (unsigned short*)d_ws;            // 8 MB
  unsigned short* Vs = Kb + (size_t)32 * T_SEQ * DH;     // 8 MB, sigma-permuted V^T
  unsigned short* WtHi = (unsigned short*)out;           // head of d_out; attn overwrites later
  unsigned short* WtLo = WtHi + 65536;
  prep_w<<<32, 256, 0, stream>>>(W, WtHi, WtLo);
  wh_gemm<<<512, 256, 0, stream>>>(h, WtHi, WtLo, Kb, Vs);
  attn<<<1024, 256, 0, stream>>>(Kb, Vs, out);
}